// Round 3
// baseline (404.817 us; speedup 1.0000x reference)
//
#include <hip/hip_runtime.h>
#include <stdint.h>

// Problem constants (fixed shapes)
#define BB 4
#define TT 4096
#define DD 1024
#define HH 1024
#define MM (BB * TT)      // 16384
#define NC 128            // scan chunks
#define CL (TT / NC)      // 32 steps per chunk

typedef __bf16 bf16x8 __attribute__((ext_vector_type(8)));
typedef float f32x4 __attribute__((ext_vector_type(4)));

// ---------------- helpers ----------------

__device__ __forceinline__ unsigned short f2bf(float f) {
    unsigned u = __float_as_uint(f);
    u += 0x7fffu + ((u >> 16) & 1u);   // round-to-nearest-even
    return (unsigned short)(u >> 16);
}

__device__ __forceinline__ float bf2f(unsigned short u) {
    return __uint_as_float(((unsigned)u) << 16);
}

__device__ __forceinline__ float softplusf(float x) {
    return (x > 15.f) ? x : log1pf(__expf(x));
}

__device__ __forceinline__ float g_fn(float x) {
    return (x >= 0.f) ? (x + 0.5f) : 1.0f / (1.0f + __expf(-x));
}

// async global->LDS, 16B per lane; hardware dest = wave-uniform base + lane*16
__device__ __forceinline__ void async_copy16(const void* gsrc, void* ldst) {
    __builtin_amdgcn_global_load_lds(
        reinterpret_cast<__attribute__((address_space(1))) unsigned int*>(
            reinterpret_cast<uintptr_t>(gsrc)),
        reinterpret_cast<__attribute__((address_space(3))) unsigned int*>(
            reinterpret_cast<uintptr_t>(ldst)),
        16, 0, 0);
}

// ---------------- fused cast kernel ----------------

__global__ void cast_all(const float* __restrict__ x,
                         const float* __restrict__ Wf,
                         const float* __restrict__ Wi,
                         const float* __restrict__ Wh,
                         unsigned short* __restrict__ xb,
                         unsigned short* __restrict__ Wb) {
    const int NX = MM * DD / 4;                 // 4194304 float4s of x
    int i = blockIdx.x * 256 + threadIdx.x;
    if (i < NX) {
        float4 v = reinterpret_cast<const float4*>(x)[i];
        ushort4 o;
        o.x = f2bf(v.x); o.y = f2bf(v.y); o.z = f2bf(v.z); o.w = f2bf(v.w);
        reinterpret_cast<ushort4*>(xb)[i] = o;
    } else {
        int j = i - NX;                         // 0 .. 786431
        if (j < 3 * 262144) {
            int which = j >> 18, k = j & 262143;
            const float* s = (which == 0) ? Wf : ((which == 1) ? Wi : Wh);
            float4 v = reinterpret_cast<const float4*>(s)[k];
            ushort4 o;
            o.x = f2bf(v.x); o.y = f2bf(v.y); o.z = f2bf(v.z); o.w = f2bf(v.w);
            reinterpret_cast<ushort4*>(Wb)[(which << 18) + k] = o;
        }
    }
}

// ---------------- fused 3-gate GEMM + gate math (v6: m201 phase port) ----
// Block 256(m) x 64(h) x 3 gates = 256 x 192 GEMM tile, BK=64.
// 8 waves = 2(m) x 4(n); per-wave 128m x 48n (3 gate-strips of 16),
// acc[3][8] f32x4 = 96 VGPR.
// LDS 112 KiB: A dbuf 2x32 KiB, B dbuf 2x24 KiB. 128-B rows, XOR swizzle
// chunk' = chunk ^ (row&7): linear global_load_lds dest + inverse-swizzled
// global source + swizzled ds_read (both-sides rule). Reads 2-way max.
// 4 phases per K-tile (mh x kh), each: {ds-load frags; stage one piece of
// tile t+1; [vmcnt]; barrier; lgkmcnt(0); setprio(1); 12 MFMA; setprio(0);
// barrier}. Counted waits only: P0 vmcnt(3), P3 vmcnt(2) (per-wave FIFO:
// tile t+1 staged as B(3 instr)@P0, A-mh0(2)@P1, A-mh1(2)@P2; P3's
// vmcnt(2) retires B+A-mh0, P0's vmcnt(3) retires A-mh1). Never 0 in loop.

#define STAGE_B(NB) do {                                                      \
    async_copy16(gB0, smem + 65536 + (NB) * 24576 +     0 + aldw); gB0 += 64; \
    async_copy16(gB1, smem + 65536 + (NB) * 24576 +  8192 + aldw); gB1 += 64; \
    async_copy16(gB2, smem + 65536 + (NB) * 24576 + 16384 + aldw); gB2 += 64; \
} while (0)

#define STAGE_A0(NB) do {                                                     \
    async_copy16(gA00, smem + (NB) * 32768 +     0 + aldw); gA00 += 64;       \
    async_copy16(gA01, smem + (NB) * 32768 + 16384 + aldw); gA01 += 64;       \
} while (0)

#define STAGE_A1(NB) do {                                                     \
    async_copy16(gA10, smem + (NB) * 32768 +  8192 + aldw); gA10 += 64;       \
    async_copy16(gA11, smem + (NB) * 32768 + 24576 + aldw); gA11 += 64;       \
} while (0)

#define LOADB(CB, ACOL) do {                                                  \
    const char* Bb_ = smem + 65536 + (CB) * 24576 + brow + (ACOL);            \
    bq0 = *reinterpret_cast<const bf16x8*>(Bb_);                              \
    bq1 = *reinterpret_cast<const bf16x8*>(Bb_ + 8192);                       \
    bq2 = *reinterpret_cast<const bf16x8*>(Bb_ + 16384);                      \
} while (0)

#define LOADA(CB, AROW, ACOL) do {                                            \
    const char* Ab_ = smem + (CB) * 32768 + (AROW) + (ACOL);                  \
    af0 = *reinterpret_cast<const bf16x8*>(Ab_);                              \
    af1 = *reinterpret_cast<const bf16x8*>(Ab_ + 2048);                       \
    af2 = *reinterpret_cast<const bf16x8*>(Ab_ + 4096);                       \
    af3 = *reinterpret_cast<const bf16x8*>(Ab_ + 6144);                       \
} while (0)

#define MFMA12(MH) do {                                                       \
    __builtin_amdgcn_s_setprio(1);                                            \
    acc[0][(MH)*4+0] = __builtin_amdgcn_mfma_f32_16x16x32_bf16(af0, bq0, acc[0][(MH)*4+0], 0, 0, 0); \
    acc[1][(MH)*4+0] = __builtin_amdgcn_mfma_f32_16x16x32_bf16(af0, bq1, acc[1][(MH)*4+0], 0, 0, 0); \
    acc[2][(MH)*4+0] = __builtin_amdgcn_mfma_f32_16x16x32_bf16(af0, bq2, acc[2][(MH)*4+0], 0, 0, 0); \
    acc[0][(MH)*4+1] = __builtin_amdgcn_mfma_f32_16x16x32_bf16(af1, bq0, acc[0][(MH)*4+1], 0, 0, 0); \
    acc[1][(MH)*4+1] = __builtin_amdgcn_mfma_f32_16x16x32_bf16(af1, bq1, acc[1][(MH)*4+1], 0, 0, 0); \
    acc[2][(MH)*4+1] = __builtin_amdgcn_mfma_f32_16x16x32_bf16(af1, bq2, acc[2][(MH)*4+1], 0, 0, 0); \
    acc[0][(MH)*4+2] = __builtin_amdgcn_mfma_f32_16x16x32_bf16(af2, bq0, acc[0][(MH)*4+2], 0, 0, 0); \
    acc[1][(MH)*4+2] = __builtin_amdgcn_mfma_f32_16x16x32_bf16(af2, bq1, acc[1][(MH)*4+2], 0, 0, 0); \
    acc[2][(MH)*4+2] = __builtin_amdgcn_mfma_f32_16x16x32_bf16(af2, bq2, acc[2][(MH)*4+2], 0, 0, 0); \
    acc[0][(MH)*4+3] = __builtin_amdgcn_mfma_f32_16x16x32_bf16(af3, bq0, acc[0][(MH)*4+3], 0, 0, 0); \
    acc[1][(MH)*4+3] = __builtin_amdgcn_mfma_f32_16x16x32_bf16(af3, bq1, acc[1][(MH)*4+3], 0, 0, 0); \
    acc[2][(MH)*4+3] = __builtin_amdgcn_mfma_f32_16x16x32_bf16(af3, bq2, acc[2][(MH)*4+3], 0, 0, 0); \
    __builtin_amdgcn_s_setprio(0);                                            \
} while (0)

#define PH_BAR()    __builtin_amdgcn_s_barrier()
#define WAIT_LGKM() asm volatile("s_waitcnt lgkmcnt(0)" ::: "memory")

#define TILE(CB, NB) do {                                                     \
    /* P0: mh0,k0 */                                                          \
    LOADB(CB, acol0); LOADA(CB, arow0, acol0);                                \
    STAGE_B(NB);                                                              \
    asm volatile("s_waitcnt vmcnt(3)" ::: "memory");                          \
    PH_BAR(); WAIT_LGKM(); MFMA12(0); PH_BAR();                               \
    /* P1: mh1,k0 */                                                          \
    LOADA(CB, arow0 + 8192, acol0);                                           \
    STAGE_A0(NB);                                                             \
    PH_BAR(); WAIT_LGKM(); MFMA12(1); PH_BAR();                               \
    /* P2: mh0,k1 */                                                          \
    LOADB(CB, acol0 ^ 64); LOADA(CB, arow0, acol0 ^ 64);                      \
    STAGE_A1(NB);                                                             \
    PH_BAR(); WAIT_LGKM(); MFMA12(0); PH_BAR();                               \
    /* P3: mh1,k1 */                                                          \
    LOADA(CB, arow0 + 8192, acol0 ^ 64);                                      \
    asm volatile("s_waitcnt vmcnt(2)" ::: "memory");                          \
    PH_BAR(); WAIT_LGKM(); MFMA12(1); PH_BAR();                               \
} while (0)

#define TILE_LAST(CB) do {                                                    \
    LOADB(CB, acol0); LOADA(CB, arow0, acol0);                                \
    asm volatile("s_waitcnt vmcnt(0)" ::: "memory");                          \
    PH_BAR(); WAIT_LGKM(); MFMA12(0);                                         \
    LOADA(CB, arow0 + 8192, acol0);        WAIT_LGKM(); MFMA12(1);            \
    LOADB(CB, acol0 ^ 64); LOADA(CB, arow0, acol0 ^ 64); WAIT_LGKM(); MFMA12(0); \
    LOADA(CB, arow0 + 8192, acol0 ^ 64);   WAIT_LGKM(); MFMA12(1);            \
} while (0)

__global__ __launch_bounds__(512, 2) void gemm_gates(
    const unsigned short* __restrict__ xb,
    const unsigned short* __restrict__ Wb,
    const float* __restrict__ bf_p, const float* __restrict__ bi_p,
    const float* __restrict__ bh_p,
    unsigned short* __restrict__ F, unsigned short* __restrict__ V) {
    __shared__ char smem[114688];   // A: 2 x 32 KiB | B: 2 x 24 KiB

    const int tid  = threadIdx.x;
    const int wave = tid >> 6;      // 0..7
    const int lane = tid & 63;

    // XCD swizzle (bijective over 1024 blocks)
    const int bidx = blockIdx.x;          // 0..1023
    const int xcd  = bidx & 7;
    const int jj   = bidx >> 3;           // 0..127
    const int bm   = ((jj & 7) << 3) | xcd;   // [0,64)
    const int bh   = jj >> 3;                 // [0,16)

    const int wm = wave >> 2;       // 0..1 : 128-row m patch
    const int wn = wave & 3;        // 0..3 : 16-col h strip (x3 gates)

    // ---- staging: per wave-instr = 8 rows x 128 B (one full K-tile row seg).
    // lane -> row srow = lane>>3, chunk slot s = lane&7; global chunk =
    // s ^ (srow&7) (inverse swizzle so linear LDS dest yields swizzled tile).
    const int srow = lane >> 3;                          // 0..7
    const int csw  = ((lane & 7) ^ srow) << 3;           // elem offset = chunk*8

    const unsigned short* gA00 = xb + (size_t)(bm * 256 +   0 + wave * 8 + srow) * DD + csw;
    const unsigned short* gA01 = xb + (size_t)(bm * 256 + 128 + wave * 8 + srow) * DD + csw;
    const unsigned short* gA10 = xb + (size_t)(bm * 256 +  64 + wave * 8 + srow) * DD + csw;
    const unsigned short* gA11 = xb + (size_t)(bm * 256 + 192 + wave * 8 + srow) * DD + csw;
    const unsigned short* gB0  = Wb + (size_t)(       0 + bh * 64 + wave * 8 + srow) * DD + csw;
    const unsigned short* gB1  = Wb + (size_t)(    1024 + bh * 64 + wave * 8 + srow) * DD + csw;
    const unsigned short* gB2  = Wb + (size_t)(    2048 + bh * 64 + wave * 8 + srow) * DD + csw;

    const int aldw = wave * 1024;   // wave's 8-row slice within a 64-row instr

    // ---- compute-side read constants ----
    // frag lane l: row base + (l&15); k-chunk = kh*4 + (l>>4); slot = chunk ^ (l&7)
    const int arow0 = (wm * 128 + (lane & 15)) * 128;        // mh0; mh1 = +8192
    const int brow  = (wn * 16  + (lane & 15)) * 128;        // + g*8192
    const int acol0 = (((lane >> 4) ^ (lane & 7)) << 4);     // k0; k1 = ^64

    f32x4 acc[3][8];
#pragma unroll
    for (int g = 0; g < 3; ++g)
#pragma unroll
        for (int mt = 0; mt < 8; ++mt)
            acc[g][mt] = (f32x4){0.f, 0.f, 0.f, 0.f};

    bf16x8 af0, af1, af2, af3;
    bf16x8 bq0, bq1, bq2;

    // ---- prologue: stage tile 0 into buf 0, drain, sync ----
    STAGE_B(0); STAGE_A0(0); STAGE_A1(0);
    asm volatile("s_waitcnt vmcnt(0)" ::: "memory");
    __builtin_amdgcn_s_barrier();

    // ---- main loop: K-tiles 0..15 (BK=64) ----
    for (int u = 0; u < 7; ++u) {   // t = 0..13
        TILE(0, 1);
        TILE(1, 0);
    }
    TILE(0, 1);                     // t = 14, stages t=15 -> buf1
    TILE_LAST(1);                   // t = 15

    // ---- epilogue: bias + normalized gates, write f and v (bf16) ----
    const int h = bh * 64 + wn * 16 + (lane & 15);
    const float bfs = bf_p[h], bis = bi_p[h], bhs = bh_p[h];
    const int mbase = bm * 256 + wm * 128 + (lane >> 4) * 4;
#pragma unroll
    for (int mt = 0; mt < 8; ++mt) {
#pragma unroll
        for (int r = 0; r < 4; ++r) {
            const int m = mbase + mt * 16 + r;
            float zf = acc[0][mt][r] + bfs;
            float zi = acc[1][mt][r] + bis;
            float zh = acc[2][mt][r] + bhs;
            float d  = softplusf(-zf) - softplusf(-zi);
            float f  = 1.0f / (1.0f + __expf(d));   // sigmoid(-d)
            float iv = 1.0f - f;                    // sigmoid(d)
            float gg = g_fn(zh);
            size_t o = (size_t)m * HH + h;
            F[o] = f2bf(f);
            V[o] = f2bf(iv * gg);
        }
    }
}

// ---------------- scan (3-pass chunked linear scan) ----------------
// h_t = f_t*h_{t-1} + v_t ; f+i=1 convex combination -> stable in fp32.
// F/V in bf16, summaries and output fp32.

__global__ void scan1_kernel(const unsigned short* __restrict__ F,
                             const unsigned short* __restrict__ V,
                             float* __restrict__ Fc, float* __restrict__ Vc) {
    const int bx = blockIdx.x, tid = threadIdx.x;
    const int c = bx & (NC - 1), b = bx >> 7;
    const ushort4* F4 = (const ushort4*)F;
    const ushort4* V4 = (const ushort4*)V;
    size_t base = ((size_t)(b * TT + c * CL) * HH) / 4 + tid;
    float4 Fp = {1.f, 1.f, 1.f, 1.f}, hv = {0.f, 0.f, 0.f, 0.f};
#pragma unroll 8
    for (int s = 0; s < CL; ++s) {
        ushort4 fu = F4[base + (size_t)s * (HH / 4)];
        ushort4 vu = V4[base + (size_t)s * (HH / 4)];
        hv.x = fmaf(bf2f(fu.x), hv.x, bf2f(vu.x)); Fp.x *= bf2f(fu.x);
        hv.y = fmaf(bf2f(fu.y), hv.y, bf2f(vu.y)); Fp.y *= bf2f(fu.y);
        hv.z = fmaf(bf2f(fu.z), hv.z, bf2f(vu.z)); Fp.z *= bf2f(fu.z);
        hv.w = fmaf(bf2f(fu.w), hv.w, bf2f(vu.w)); Fp.w *= bf2f(fu.w);
    }
    size_t ci = ((size_t)(b * NC + c) * HH) / 4 + tid;
    ((float4*)Fc)[ci] = Fp;
    ((float4*)Vc)[ci] = hv;
}

__global__ void scan2_kernel(const float* __restrict__ h0,
                             const float* __restrict__ Fc,
                             const float* __restrict__ Vc,
                             float* __restrict__ Hin) {
    const int gid = blockIdx.x * 256 + threadIdx.x;   // 0..4095
    const int b = gid >> 10, h = gid & (HH - 1);
    float carry = g_fn(h0[gid]);
#pragma unroll 8
    for (int c = 0; c < NC; ++c) {
        int ci = (b * NC + c) * HH + h;
        Hin[ci] = carry;
        carry = fmaf(Fc[ci], carry, Vc[ci]);
    }
}

__global__ void scan3_kernel(const unsigned short* __restrict__ F,
                             const unsigned short* __restrict__ V,
                             const float* __restrict__ Hin,
                             float* __restrict__ Out) {
    const int bx = blockIdx.x, tid = threadIdx.x;
    const int c = bx & (NC - 1), b = bx >> 7;
    const ushort4* F4 = (const ushort4*)F;
    const ushort4* V4 = (const ushort4*)V;
    float4* O4 = (float4*)Out;
    size_t base = ((size_t)(b * TT + c * CL) * HH) / 4 + tid;
    size_t ci = ((size_t)(b * NC + c) * HH) / 4 + tid;
    float4 carry = ((const float4*)Hin)[ci];
#pragma unroll 8
    for (int s = 0; s < CL; ++s) {
        size_t idx = base + (size_t)s * (HH / 4);
        ushort4 fu = F4[idx];
        ushort4 vu = V4[idx];
        carry.x = fmaf(bf2f(fu.x), carry.x, bf2f(vu.x));
        carry.y = fmaf(bf2f(fu.y), carry.y, bf2f(vu.y));
        carry.z = fmaf(bf2f(fu.z), carry.z, bf2f(vu.z));
        carry.w = fmaf(bf2f(fu.w), carry.w, bf2f(vu.w));
        O4[idx] = carry;
    }
}

// ---------------- launch ----------------

extern "C" void kernel_launch(void* const* d_in, const int* in_sizes, int n_in,
                              void* d_out, int out_size, void* d_ws, size_t ws_size,
                              hipStream_t stream) {
    const float* x   = (const float*)d_in[0];
    const float* h0  = (const float*)d_in[1];
    const float* Wf  = (const float*)d_in[2];
    const float* bfp = (const float*)d_in[3];
    const float* Wi  = (const float*)d_in[4];
    const float* bip = (const float*)d_in[5];
    const float* Wh  = (const float*)d_in[6];
    const float* bhp = (const float*)d_in[7];
    float* out = (float*)d_out;

    char* ws = (char*)d_ws;
    unsigned short* xb = (unsigned short*)ws;                   // 32 MiB bf16 x
    unsigned short* Wb = (unsigned short*)(ws + 33554432);      // 6 MiB bf16 W
    unsigned short* Fb = (unsigned short*)(ws + 39845888);      // 32 MiB bf16 f
    unsigned short* Vb = (unsigned short*)(ws + 73400320);      // 32 MiB bf16 v
    float* Fc  = (float*)(ws);                                  // 2 MiB (aliases xb)
    float* Vc  = (float*)(ws + 2097152);                        // 2 MiB
    float* Hin = (float*)(ws + 4194304);                        // 2 MiB

    cast_all<<<19456, 256, 0, stream>>>(x, Wf, Wi, Wh, xb, Wb);
    gemm_gates<<<1024, 512, 0, stream>>>(xb, Wb, bfp, bip, bhp, Fb, Vb);
    scan1_kernel<<<BB * NC, 256, 0, stream>>>(Fb, Vb, Fc, Vc);
    scan2_kernel<<<16, 256, 0, stream>>>(h0, Fc, Vc, Hin);
    scan3_kernel<<<BB * NC, 256, 0, stream>>>(Fb, Vb, Hin, out);
}

// Round 4
// 366.311 us; speedup vs baseline: 1.1051x; 1.1051x over previous
//
#include <hip/hip_runtime.h>
#include <stdint.h>

// Problem constants (fixed shapes)
#define BB 4
#define TT 4096
#define DD 1024
#define HH 1024
#define MM (BB * TT)      // 16384
#define NC 128            // scan chunks
#define CL (TT / NC)      // 32 steps per chunk

typedef __bf16 bf16x8 __attribute__((ext_vector_type(8)));
typedef short  s16x8  __attribute__((ext_vector_type(8)));
typedef float  f32x4  __attribute__((ext_vector_type(4)));

// ---------------- helpers ----------------

__device__ __forceinline__ unsigned short f2bf(float f) {
    unsigned u = __float_as_uint(f);
    u += 0x7fffu + ((u >> 16) & 1u);   // round-to-nearest-even
    return (unsigned short)(u >> 16);
}

__device__ __forceinline__ float bf2f(unsigned short u) {
    return __uint_as_float(((unsigned)u) << 16);
}

__device__ __forceinline__ float softplusf(float x) {
    return (x > 15.f) ? x : log1pf(__expf(x));
}

__device__ __forceinline__ float g_fn(float x) {
    return (x >= 0.f) ? (x + 0.5f) : 1.0f / (1.0f + __expf(-x));
}

// MFMA wrapper: fragments live as i16 vectors (clean ds_read_b128 codegen,
// guide-verified pattern); bit_cast to the builtin's bf16 vector type is an
// IR-level no-op.
__device__ __forceinline__ f32x4 mfma_bf16(s16x8 a, s16x8 b, f32x4 c) {
    return __builtin_amdgcn_mfma_f32_16x16x32_bf16(
        __builtin_bit_cast(bf16x8, a), __builtin_bit_cast(bf16x8, b), c, 0, 0, 0);
}

// async global->LDS, 16B per lane; hardware dest = wave-uniform base + lane*16
__device__ __forceinline__ void async_copy16(const void* gsrc, void* ldst) {
    __builtin_amdgcn_global_load_lds(
        reinterpret_cast<__attribute__((address_space(1))) unsigned int*>(
            reinterpret_cast<uintptr_t>(gsrc)),
        reinterpret_cast<__attribute__((address_space(3))) unsigned int*>(
            reinterpret_cast<uintptr_t>(ldst)),
        16, 0, 0);
}

// ---------------- fused cast kernel ----------------

__global__ void cast_all(const float* __restrict__ x,
                         const float* __restrict__ Wf,
                         const float* __restrict__ Wi,
                         const float* __restrict__ Wh,
                         unsigned short* __restrict__ xb,
                         unsigned short* __restrict__ Wb) {
    const int NX = MM * DD / 4;                 // 4194304 float4s of x
    int i = blockIdx.x * 256 + threadIdx.x;
    if (i < NX) {
        float4 v = reinterpret_cast<const float4*>(x)[i];
        ushort4 o;
        o.x = f2bf(v.x); o.y = f2bf(v.y); o.z = f2bf(v.z); o.w = f2bf(v.w);
        reinterpret_cast<ushort4*>(xb)[i] = o;
    } else {
        int j = i - NX;                         // 0 .. 786431
        if (j < 3 * 262144) {
            int which = j >> 18, k = j & 262143;
            const float* s = (which == 0) ? Wf : ((which == 1) ? Wi : Wh);
            float4 v = reinterpret_cast<const float4*>(s)[k];
            ushort4 o;
            o.x = f2bf(v.x); o.y = f2bf(v.y); o.z = f2bf(v.z); o.w = f2bf(v.w);
            reinterpret_cast<ushort4*>(Wb)[(which << 18) + k] = o;
        }
    }
}

// ---------------- fused 3-gate GEMM + gate math ----------------
// Structure = the proven R0 kernel (246 us) VERBATIM; the ONLY change is
// fragment dtype: LDS->reg loads are s16x8 (i16 vectors) instead of
// __bf16 vectors, bit_cast at the MFMA call. Theory: <8 x bfloat>
// load/copy legalization scalarizes (~8-16 VALU per fragment), producing
// the measured real-VALU ~47% that pins MfmaUtil at 18%.
// Block tile: 128(m) x 64(h), 3 gates; 512 threads = 8 waves in 4x2, each
// wave a 32x32 patch x 3 gates -> 48 acc regs/lane.
//  (a) double-buffered LDS (80 KiB, 2 blocks/CU) with AITER-style
//      s_waitcnt vmcnt(5) + RAW s_barrier (no compiler vmcnt(0) drain).
//  (b) XCD swizzle: concurrent blocks on one XCD share bh -> B L2-resident.

#define ISSUE(NB) do {                                                        \
    _Pragma("unroll")                                                         \
    for (int j = 0; j < 2; ++j)                                               \
        async_copy16(gptrA[j], smem + loffA[j] + (NB) * 16384);               \
    _Pragma("unroll")                                                         \
    for (int j = 0; j < 3; ++j)                                               \
        async_copy16(gptrB[j], smem + 32768 + loffB[j] + (NB) * 24576);       \
    _Pragma("unroll")                                                         \
    for (int j = 0; j < 2; ++j) gptrA[j] += 64;                               \
    _Pragma("unroll")                                                         \
    for (int j = 0; j < 3; ++j) gptrB[j] += 64;                               \
} while (0)

#define COMPUTE(CB) do {                                                      \
    const char* Ab = smem + (CB) * 16384;                                     \
    const char* Bb = smem + 32768 + (CB) * 24576;                             \
    _Pragma("unroll")                                                         \
    for (int ks = 0; ks < 2; ++ks) {                                          \
        const int px = pc ^ (ks << 6);                                        \
        s16x8 af[2];                                                          \
        _Pragma("unroll")                                                     \
        for (int mt = 0; mt < 2; ++mt)                                        \
            af[mt] = *reinterpret_cast<const s16x8*>(Ab + arow + mt * 2048 + px); \
        s16x8 bfr[3][2];                                                      \
        _Pragma("unroll")                                                     \
        for (int g = 0; g < 3; ++g)                                           \
            _Pragma("unroll")                                                 \
            for (int nt = 0; nt < 2; ++nt)                                    \
                bfr[g][nt] = *reinterpret_cast<const s16x8*>(                 \
                    Bb + g * 8192 + brow + nt * 2048 + px);                   \
        _Pragma("unroll")                                                     \
        for (int g = 0; g < 3; ++g)                                           \
            _Pragma("unroll")                                                 \
            for (int mt = 0; mt < 2; ++mt)                                    \
                _Pragma("unroll")                                             \
                for (int nt = 0; nt < 2; ++nt)                                \
                    acc[g][mt][nt] = mfma_bf16(af[mt], bfr[g][nt],            \
                                               acc[g][mt][nt]);               \
    }                                                                         \
} while (0)

#define STEP(CB, NB, LAST) do {                                               \
    if (!(LAST)) {                                                            \
        ISSUE(NB);                                                            \
        asm volatile("s_waitcnt vmcnt(5)" ::: "memory");                      \
    } else {                                                                  \
        asm volatile("s_waitcnt vmcnt(0)" ::: "memory");                      \
    }                                                                         \
    __builtin_amdgcn_s_barrier();                                             \
    COMPUTE(CB);                                                              \
    asm volatile("s_waitcnt lgkmcnt(0)" ::: "memory");                        \
    __builtin_amdgcn_s_barrier();                                             \
} while (0)

__global__ __launch_bounds__(512, 4) void gemm_gates(
    const unsigned short* __restrict__ xb,
    const unsigned short* __restrict__ Wb,
    const float* __restrict__ bf_p, const float* __restrict__ bi_p,
    const float* __restrict__ bh_p,
    unsigned short* __restrict__ F, unsigned short* __restrict__ V) {
    __shared__ char smem[81920];        // A0|A1 (32 KiB) + B0|B1 (48 KiB)

    const int tid  = threadIdx.x;
    const int wave = tid >> 6;          // 0..7
    const int lane = tid & 63;

    // XCD swizzle: dispatch order i -> XCD i%8. Make concurrent blocks on
    // one XCD share bh so the 384 KB B slice is L2-resident (4 MiB/XCD).
    const int bi  = blockIdx.x;         // 0..2047
    const int xcd = bi & 7;
    const int jj  = bi >> 3;            // 0..255 per-XCD stream
    const int bm  = ((jj & 15) << 3) | xcd;   // [0,128)
    const int bh  = jj >> 4;                  // [0,16)

    const int pm   = wave >> 1;         // 0..3  (32-row m patch)
    const int ph   = wave & 1;          // 0..1  (32-col h patch)

    // staging: lane writes LDS row lr, chunk (lane&7); fetches global chunk
    // (lane&7)^lr  (XOR swizzle, conflict-free).
    const int lr = lane >> 3;
    const int gc = (((lane & 7) ^ lr) << 3);

    const unsigned short* gptrA[2];
    const unsigned short* gptrB[3];
    int loffA[2], loffB[3];
#pragma unroll
    for (int j = 0; j < 2; ++j) {
        int s = wave + j * 8;           // 0..15
        int row = bm * 128 + s * 8 + lr;
        gptrA[j] = xb + (size_t)row * DD + gc;
        loffA[j] = s * 1024;
    }
#pragma unroll
    for (int j = 0; j < 3; ++j) {       // gate j, row-seg = wave
        int row = j * HH + bh * 64 + wave * 8 + lr;
        gptrB[j] = Wb + (size_t)row * DD + gc;
        loffB[j] = (j * 8 + wave) * 1024;
    }

    // compute-side lane constants (byte offsets)
    const int pc   = (((lane >> 4) ^ (lane & 7)) << 4);
    const int arow = (pm * 32 + (lane & 15)) * 128;
    const int brow = (ph * 32 + (lane & 15)) * 128;

    f32x4 acc[3][2][2];
#pragma unroll
    for (int g = 0; g < 3; ++g)
#pragma unroll
        for (int mt = 0; mt < 2; ++mt)
#pragma unroll
            for (int nt = 0; nt < 2; ++nt)
                acc[g][mt][nt] = (f32x4){0.f, 0.f, 0.f, 0.f};

    ISSUE(0);                           // prologue: tile 0 -> buf 0
    for (int t = 0; t < 7; ++t) {       // kb = 0..13
        STEP(0, 1, 0);
        STEP(1, 0, 0);
    }
    STEP(0, 1, 0);                      // kb = 14, prefetch tile15 -> buf1
    STEP(1, 0, 1);                      // kb = 15, last

    // epilogue: bias + normalized gates, write f and v (bf16)
    const int m0  = bm * 128 + pm * 32 + (lane >> 4) * 4;
    const int h0i = bh * 64 + ph * 32 + (lane & 15);
#pragma unroll
    for (int nt = 0; nt < 2; ++nt) {
        const int h = h0i + nt * 16;
        const float bfs = bf_p[h], bis = bi_p[h], bhs = bh_p[h];
#pragma unroll
        for (int mt = 0; mt < 2; ++mt) {
#pragma unroll
            for (int r = 0; r < 4; ++r) {
                const int m = m0 + mt * 16 + r;
                float zf = acc[0][mt][nt][r] + bfs;
                float zi = acc[1][mt][nt][r] + bis;
                float zh = acc[2][mt][nt][r] + bhs;
                float d  = softplusf(-zf) - softplusf(-zi);
                float f  = 1.0f / (1.0f + __expf(d));   // sigmoid(-d)
                float iv = 1.0f - f;                    // sigmoid(d)
                float gg = g_fn(zh);
                size_t o = (size_t)m * HH + h;
                F[o] = f2bf(f);
                V[o] = f2bf(iv * gg);
            }
        }
    }
}

// ---------------- scan (3-pass chunked linear scan) ----------------
// h_t = f_t*h_{t-1} + v_t ; f+i=1 convex combination -> stable in fp32.
// F/V in bf16, summaries and output fp32.

__global__ void scan1_kernel(const unsigned short* __restrict__ F,
                             const unsigned short* __restrict__ V,
                             float* __restrict__ Fc, float* __restrict__ Vc) {
    const int bx = blockIdx.x, tid = threadIdx.x;
    const int c = bx & (NC - 1), b = bx >> 7;
    const ushort4* F4 = (const ushort4*)F;
    const ushort4* V4 = (const ushort4*)V;
    size_t base = ((size_t)(b * TT + c * CL) * HH) / 4 + tid;
    float4 Fp = {1.f, 1.f, 1.f, 1.f}, hv = {0.f, 0.f, 0.f, 0.f};
#pragma unroll 8
    for (int s = 0; s < CL; ++s) {
        ushort4 fu = F4[base + (size_t)s * (HH / 4)];
        ushort4 vu = V4[base + (size_t)s * (HH / 4)];
        hv.x = fmaf(bf2f(fu.x), hv.x, bf2f(vu.x)); Fp.x *= bf2f(fu.x);
        hv.y = fmaf(bf2f(fu.y), hv.y, bf2f(vu.y)); Fp.y *= bf2f(fu.y);
        hv.z = fmaf(bf2f(fu.z), hv.z, bf2f(vu.z)); Fp.z *= bf2f(fu.z);
        hv.w = fmaf(bf2f(fu.w), hv.w, bf2f(vu.w)); Fp.w *= bf2f(fu.w);
    }
    size_t ci = ((size_t)(b * NC + c) * HH) / 4 + tid;
    ((float4*)Fc)[ci] = Fp;
    ((float4*)Vc)[ci] = hv;
}

__global__ void scan2_kernel(const float* __restrict__ h0,
                             const float* __restrict__ Fc,
                             const float* __restrict__ Vc,
                             float* __restrict__ Hin) {
    const int gid = blockIdx.x * 256 + threadIdx.x;   // 0..4095
    const int b = gid >> 10, h = gid & (HH - 1);
    float carry = g_fn(h0[gid]);
#pragma unroll 8
    for (int c = 0; c < NC; ++c) {
        int ci = (b * NC + c) * HH + h;
        Hin[ci] = carry;
        carry = fmaf(Fc[ci], carry, Vc[ci]);
    }
}

__global__ void scan3_kernel(const unsigned short* __restrict__ F,
                             const unsigned short* __restrict__ V,
                             const float* __restrict__ Hin,
                             float* __restrict__ Out) {
    const int bx = blockIdx.x, tid = threadIdx.x;
    const int c = bx & (NC - 1), b = bx >> 7;
    const ushort4* F4 = (const ushort4*)F;
    const ushort4* V4 = (const ushort4*)V;
    float4* O4 = (float4*)Out;
    size_t base = ((size_t)(b * TT + c * CL) * HH) / 4 + tid;
    size_t ci = ((size_t)(b * NC + c) * HH) / 4 + tid;
    float4 carry = ((const float4*)Hin)[ci];
#pragma unroll 8
    for (int s = 0; s < CL; ++s) {
        size_t idx = base + (size_t)s * (HH / 4);
        ushort4 fu = F4[idx];
        ushort4 vu = V4[idx];
        carry.x = fmaf(bf2f(fu.x), carry.x, bf2f(vu.x));
        carry.y = fmaf(bf2f(fu.y), carry.y, bf2f(vu.y));
        carry.z = fmaf(bf2f(fu.z), carry.z, bf2f(vu.z));
        carry.w = fmaf(bf2f(fu.w), carry.w, bf2f(vu.w));
        O4[idx] = carry;
    }
}

// ---------------- launch ----------------

extern "C" void kernel_launch(void* const* d_in, const int* in_sizes, int n_in,
                              void* d_out, int out_size, void* d_ws, size_t ws_size,
                              hipStream_t stream) {
    const float* x   = (const float*)d_in[0];
    const float* h0  = (const float*)d_in[1];
    const float* Wf  = (const float*)d_in[2];
    const float* bfp = (const float*)d_in[3];
    const float* Wi  = (const float*)d_in[4];
    const float* bip = (const float*)d_in[5];
    const float* Wh  = (const float*)d_in[6];
    const float* bhp = (const float*)d_in[7];
    float* out = (float*)d_out;

    char* ws = (char*)d_ws;
    unsigned short* xb = (unsigned short*)ws;                   // 32 MiB bf16 x
    unsigned short* Wb = (unsigned short*)(ws + 33554432);      // 6 MiB bf16 W
    unsigned short* Fb = (unsigned short*)(ws + 39845888);      // 32 MiB bf16 f
    unsigned short* Vb = (unsigned short*)(ws + 73400320);      // 32 MiB bf16 v
    float* Fc  = (float*)(ws);                                  // 2 MiB (aliases xb)
    float* Vc  = (float*)(ws + 2097152);                        // 2 MiB
    float* Hin = (float*)(ws + 4194304);                        // 2 MiB

    cast_all<<<19456, 256, 0, stream>>>(x, Wf, Wi, Wh, xb, Wb);
    gemm_gates<<<2048, 512, 0, stream>>>(xb, Wb, bfp, bip, bhp, Fb, Vb);
    scan1_kernel<<<BB * NC, 256, 0, stream>>>(Fb, Vb, Fc, Vc);
    scan2_kernel<<<16, 256, 0, stream>>>(h0, Fc, Vc, Hin);
    scan3_kernel<<<BB * NC, 256, 0, stream>>>(Fb, Vb, Hin, out);
}

// Round 5
// 293.315 us; speedup vs baseline: 1.3801x; 1.2489x over previous
//
#include <hip/hip_runtime.h>
#include <stdint.h>

// Problem constants (fixed shapes)
#define BB 4
#define TT 4096
#define DD 1024
#define HH 1024
#define MM (BB * TT)      // 16384
#define NC 128            // scan chunks
#define CL (TT / NC)      // 32 steps per chunk

typedef __bf16 bf16x8 __attribute__((ext_vector_type(8)));
typedef short  s16x8  __attribute__((ext_vector_type(8)));
typedef float  f32x4  __attribute__((ext_vector_type(4)));
typedef float  f32x16 __attribute__((ext_vector_type(16)));

// ---------------- helpers ----------------

__device__ __forceinline__ unsigned short f2bf(float f) {
    unsigned u = __float_as_uint(f);
    u += 0x7fffu + ((u >> 16) & 1u);   // round-to-nearest-even
    return (unsigned short)(u >> 16);
}

__device__ __forceinline__ float bf2f(unsigned short u) {
    return __uint_as_float(((unsigned)u) << 16);
}

__device__ __forceinline__ float g_fn(float x) {
    return (x >= 0.f) ? (x + 0.5f) : 1.0f / (1.0f + __expf(-x));
}

// MFMA wrapper: fragments live as i16 vectors (clean ds_read_b128 codegen);
// bit_cast to the builtin's bf16 vector type is an IR-level no-op.
__device__ __forceinline__ f32x16 mfma32(s16x8 a, s16x8 b, f32x16 c) {
    return __builtin_amdgcn_mfma_f32_32x32x16_bf16(
        __builtin_bit_cast(bf16x8, a), __builtin_bit_cast(bf16x8, b), c, 0, 0, 0);
}

// async global->LDS, 16B per lane; hardware dest = wave-uniform base + lane*16
__device__ __forceinline__ void async_copy16(const void* gsrc, void* ldst) {
    __builtin_amdgcn_global_load_lds(
        reinterpret_cast<__attribute__((address_space(1))) unsigned int*>(
            reinterpret_cast<uintptr_t>(gsrc)),
        reinterpret_cast<__attribute__((address_space(3))) unsigned int*>(
            reinterpret_cast<uintptr_t>(ldst)),
        16, 0, 0);
}

// ---------------- fused cast kernel ----------------

__global__ void cast_all(const float* __restrict__ x,
                         const float* __restrict__ Wf,
                         const float* __restrict__ Wi,
                         const float* __restrict__ Wh,
                         unsigned short* __restrict__ xb,
                         unsigned short* __restrict__ Wb) {
    const int NX = MM * DD / 4;                 // 4194304 float4s of x
    int i = blockIdx.x * 256 + threadIdx.x;
    if (i < NX) {
        float4 v = reinterpret_cast<const float4*>(x)[i];
        ushort4 o;
        o.x = f2bf(v.x); o.y = f2bf(v.y); o.z = f2bf(v.z); o.w = f2bf(v.w);
        reinterpret_cast<ushort4*>(xb)[i] = o;
    } else {
        int j = i - NX;                         // 0 .. 786431
        if (j < 3 * 262144) {
            int which = j >> 18, k = j & 262143;
            const float* s = (which == 0) ? Wf : ((which == 1) ? Wi : Wh);
            float4 v = reinterpret_cast<const float4*>(s)[k];
            ushort4 o;
            o.x = f2bf(v.x); o.y = f2bf(v.y); o.z = f2bf(v.z); o.w = f2bf(v.w);
            reinterpret_cast<ushort4*>(Wb)[(which << 18) + k] = o;
        }
    }
}

// ---------------- fused 3-gate GEMM + gate math (v8) ----------------
// Same proven schedule/staging/swizzle as R4; the levers vs R4:
//  (1) mfma_f32_32x32x16_bf16 (half the MFMA instrs per FLOP; ceiling
//      2382 vs 2075 TF),
//  (2) per-wave patch 64m x 32h x 3g (acc[3][2] f32x16 = 96 regs):
//      fragment reads per FLOP drop 1.6x (20 b128 per 786 KFLOP),
//  (3) 256-thread blocks (4 waves, 2pm x 2ph); same 128m x (64h x 3g)
//      block tile, BK=64, 80 KiB dbuf -> still 2 blocks/CU,
//  (4) exp-form epilogue: f=(1+eb)/(2+ea+eb), iv=(1+ea)/(2+ea+eb) --
//      no log1p, no precise-div chains.
// A/B frag layout (32x32x16): row/col = lane&31, k = (lane>>5)*8+e.
// C/D: row = (reg&3)+8*(reg>>2)+4*(lane>>5), col = lane&31 [m74/m101].
// LDS rows 128 B, slot = chunk ^ (row&7) swizzle; staging identical to R4
// (8-row segments, inverse-swizzled global source, linear LDS dest).

#define ISSUE(NB) do {                                                        \
    _Pragma("unroll")                                                         \
    for (int j = 0; j < 4; ++j)                                               \
        async_copy16(gptrA[j], smem + loffA[j] + (NB) * 16384);               \
    _Pragma("unroll")                                                         \
    for (int j = 0; j < 6; ++j)                                               \
        async_copy16(gptrB[j], smem + 32768 + loffB[j] + (NB) * 24576);       \
    _Pragma("unroll")                                                         \
    for (int j = 0; j < 4; ++j) gptrA[j] += 64;                               \
    _Pragma("unroll")                                                         \
    for (int j = 0; j < 6; ++j) gptrB[j] += 64;                               \
} while (0)

#define COMPUTE(CB) do {                                                      \
    const char* Ab = smem + (CB) * 16384;                                     \
    const char* Bb = smem + 32768 + (CB) * 24576;                             \
    _Pragma("unroll")                                                         \
    for (int ks = 0; ks < 4; ++ks) {                                          \
        const int col = c0 ^ (ks << 5);                                       \
        s16x8 a0 = *reinterpret_cast<const s16x8*>(Ab + arowb + col);         \
        s16x8 a1 = *reinterpret_cast<const s16x8*>(Ab + arowb + 4096 + col);  \
        s16x8 b0 = *reinterpret_cast<const s16x8*>(Bb + browb + col);         \
        s16x8 b1 = *reinterpret_cast<const s16x8*>(Bb + browb + 8192 + col);  \
        s16x8 b2 = *reinterpret_cast<const s16x8*>(Bb + browb + 16384 + col); \
        acc[0][0] = mfma32(a0, b0, acc[0][0]);                                \
        acc[0][1] = mfma32(a1, b0, acc[0][1]);                                \
        acc[1][0] = mfma32(a0, b1, acc[1][0]);                                \
        acc[1][1] = mfma32(a1, b1, acc[1][1]);                                \
        acc[2][0] = mfma32(a0, b2, acc[2][0]);                                \
        acc[2][1] = mfma32(a1, b2, acc[2][1]);                                \
    }                                                                         \
} while (0)

#define STEP(CB, NB, LAST) do {                                               \
    if (!(LAST)) {                                                            \
        ISSUE(NB);                                                            \
        asm volatile("s_waitcnt vmcnt(10)" ::: "memory");                     \
    } else {                                                                  \
        asm volatile("s_waitcnt vmcnt(0)" ::: "memory");                      \
    }                                                                         \
    __builtin_amdgcn_s_barrier();                                             \
    COMPUTE(CB);                                                              \
    asm volatile("s_waitcnt lgkmcnt(0)" ::: "memory");                        \
    __builtin_amdgcn_s_barrier();                                             \
} while (0)

__global__ __launch_bounds__(256, 2) void gemm_gates(
    const unsigned short* __restrict__ xb,
    const unsigned short* __restrict__ Wb,
    const float* __restrict__ bf_p, const float* __restrict__ bi_p,
    const float* __restrict__ bh_p,
    unsigned short* __restrict__ F, unsigned short* __restrict__ V) {
    __shared__ char smem[81920];        // A0|A1 (32 KiB) + B0|B1 (48 KiB)

    const int tid  = threadIdx.x;
    const int wave = tid >> 6;          // 0..3
    const int lane = tid & 63;

    // XCD swizzle: dispatch order i -> XCD i%8. Concurrent blocks on one
    // XCD share bh so the 384 KB B slice is L2-resident (4 MiB/XCD).
    const int bi  = blockIdx.x;         // 0..2047
    const int xcd = bi & 7;
    const int jj  = bi >> 3;            // 0..255 per-XCD stream
    const int bm  = ((jj & 15) << 3) | xcd;   // [0,128)
    const int bh  = jj >> 4;                  // [0,16)

    const int pm   = wave >> 1;         // 0..1  (64-row m patch)
    const int ph   = wave & 1;          // 0..1  (32-col h patch)

    // staging: lane writes LDS row lr, slot (lane&7); fetches global chunk
    // (lane&7)^lr  (XOR swizzle; slot s of row r holds chunk s^r).
    const int lr = lane >> 3;
    const int gc = (((lane & 7) ^ lr) << 3);

    const unsigned short* gptrA[4];
    const unsigned short* gptrB[6];
    int loffA[4], loffB[6];
#pragma unroll
    for (int j = 0; j < 4; ++j) {
        int s = wave + j * 4;           // 0..15
        int row = bm * 128 + s * 8 + lr;
        gptrA[j] = xb + (size_t)row * DD + gc;
        loffA[j] = s * 1024;
    }
#pragma unroll
    for (int j = 0; j < 6; ++j) {
        int s = wave + j * 4;           // 0..23: gate = s>>3, h-seg = s&7
        int row = (s >> 3) * HH + bh * 64 + (s & 7) * 8 + lr;
        gptrB[j] = Wb + (size_t)row * DD + gc;
        loffB[j] = s * 1024;
    }

    // compute-side lane constants (byte offsets)
    // frag: row = base + (lane&31); k-chunk = ks*2 + (lane>>5);
    // slot = chunk ^ (row&7), row&7 == lane&7  ->  col = c0 ^ (ks<<5)
    const int c0    = (((lane >> 5) ^ (lane & 7)) << 4);
    const int arowb = (pm * 64 + (lane & 31)) * 128;   // mt=1 -> +4096
    const int browb = (ph * 32 + (lane & 31)) * 128;   // gate g -> +g*8192

    f32x16 acc[3][2];
#pragma unroll
    for (int g = 0; g < 3; ++g)
#pragma unroll
        for (int mt = 0; mt < 2; ++mt)
            acc[g][mt] = (f32x16)(0.f);

    ISSUE(0);                           // prologue: tile 0 -> buf 0
    for (int t = 0; t < 7; ++t) {       // kb = 0..13
        STEP(0, 1, 0);
        STEP(1, 0, 0);
    }
    STEP(0, 1, 0);                      // kb = 14, prefetch tile15 -> buf1
    STEP(1, 0, 1);                      // kb = 15, last

    // epilogue: bias + normalized gates (exp form), write f and v (bf16)
    const int h   = bh * 64 + ph * 32 + (lane & 31);
    const float bfs = bf_p[h], bis = bi_p[h], bhs = bh_p[h];
    const int mb  = bm * 128 + pm * 64 + ((lane >> 5) << 2);
#pragma unroll
    for (int mt = 0; mt < 2; ++mt) {
#pragma unroll
        for (int r = 0; r < 16; ++r) {
            const int m = mb + mt * 32 + (r & 3) + ((r >> 2) << 3);
            float zf = acc[0][mt][r] + bfs;
            float zi = acc[1][mt][r] + bis;
            float zh = acc[2][mt][r] + bhs;
            // f = sigmoid(-d), iv = sigmoid(d), d = sp(-zf)-sp(-zi)
            //   = (1+eb)/(2+ea+eb), (1+ea)/(2+ea+eb); clamp avoids inf/inf
            float ea = __expf(fminf(-zf, 60.f));
            float eb = __expf(fminf(-zi, 60.f));
            float s  = __builtin_amdgcn_rcpf(2.f + ea + eb);
            float fv = (1.f + eb) * s;
            float iv = (1.f + ea) * s;
            float gg = (zh >= 0.f) ? (zh + 0.5f)
                                   : __builtin_amdgcn_rcpf(1.f + __expf(-zh));
            size_t o = (size_t)m * HH + h;
            F[o] = f2bf(fv);
            V[o] = f2bf(iv * gg);
        }
    }
}

// ---------------- scan (3-pass chunked linear scan) ----------------
// h_t = f_t*h_{t-1} + v_t ; f+i=1 convex combination -> stable in fp32.
// F/V in bf16, summaries and output fp32.

__global__ void scan1_kernel(const unsigned short* __restrict__ F,
                             const unsigned short* __restrict__ V,
                             float* __restrict__ Fc, float* __restrict__ Vc) {
    const int bx = blockIdx.x, tid = threadIdx.x;
    const int c = bx & (NC - 1), b = bx >> 7;
    const ushort4* F4 = (const ushort4*)F;
    const ushort4* V4 = (const ushort4*)V;
    size_t base = ((size_t)(b * TT + c * CL) * HH) / 4 + tid;
    float4 Fp = {1.f, 1.f, 1.f, 1.f}, hv = {0.f, 0.f, 0.f, 0.f};
#pragma unroll 8
    for (int s = 0; s < CL; ++s) {
        ushort4 fu = F4[base + (size_t)s * (HH / 4)];
        ushort4 vu = V4[base + (size_t)s * (HH / 4)];
        hv.x = fmaf(bf2f(fu.x), hv.x, bf2f(vu.x)); Fp.x *= bf2f(fu.x);
        hv.y = fmaf(bf2f(fu.y), hv.y, bf2f(vu.y)); Fp.y *= bf2f(fu.y);
        hv.z = fmaf(bf2f(fu.z), hv.z, bf2f(vu.z)); Fp.z *= bf2f(fu.z);
        hv.w = fmaf(bf2f(fu.w), hv.w, bf2f(vu.w)); Fp.w *= bf2f(fu.w);
    }
    size_t ci = ((size_t)(b * NC + c) * HH) / 4 + tid;
    ((float4*)Fc)[ci] = Fp;
    ((float4*)Vc)[ci] = hv;
}

__global__ void scan2_kernel(const float* __restrict__ h0,
                             const float* __restrict__ Fc,
                             const float* __restrict__ Vc,
                             float* __restrict__ Hin) {
    const int gid = blockIdx.x * 256 + threadIdx.x;   // 0..4095
    const int b = gid >> 10, h = gid & (HH - 1);
    float carry = g_fn(h0[gid]);
#pragma unroll 8
    for (int c = 0; c < NC; ++c) {
        int ci = (b * NC + c) * HH + h;
        Hin[ci] = carry;
        carry = fmaf(Fc[ci], carry, Vc[ci]);
    }
}

__global__ void scan3_kernel(const unsigned short* __restrict__ F,
                             const unsigned short* __restrict__ V,
                             const float* __restrict__ Hin,
                             float* __restrict__ Out) {
    const int bx = blockIdx.x, tid = threadIdx.x;
    const int c = bx & (NC - 1), b = bx >> 7;
    const ushort4* F4 = (const ushort4*)F;
    const ushort4* V4 = (const ushort4*)V;
    float4* O4 = (float4*)Out;
    size_t base = ((size_t)(b * TT + c * CL) * HH) / 4 + tid;
    size_t ci = ((size_t)(b * NC + c) * HH) / 4 + tid;
    float4 carry = ((const float4*)Hin)[ci];
#pragma unroll 8
    for (int s = 0; s < CL; ++s) {
        size_t idx = base + (size_t)s * (HH / 4);
        ushort4 fu = F4[idx];
        ushort4 vu = V4[idx];
        carry.x = fmaf(bf2f(fu.x), carry.x, bf2f(vu.x));
        carry.y = fmaf(bf2f(fu.y), carry.y, bf2f(vu.y));
        carry.z = fmaf(bf2f(fu.z), carry.z, bf2f(vu.z));
        carry.w = fmaf(bf2f(fu.w), carry.w, bf2f(vu.w));
        O4[idx] = carry;
    }
}

// ---------------- launch ----------------

extern "C" void kernel_launch(void* const* d_in, const int* in_sizes, int n_in,
                              void* d_out, int out_size, void* d_ws, size_t ws_size,
                              hipStream_t stream) {
    const float* x   = (const float*)d_in[0];
    const float* h0  = (const float*)d_in[1];
    const float* Wf  = (const float*)d_in[2];
    const float* bfp = (const float*)d_in[3];
    const float* Wi  = (const float*)d_in[4];
    const float* bip = (const float*)d_in[5];
    const float* Wh  = (const float*)d_in[6];
    const float* bhp = (const float*)d_in[7];
    float* out = (float*)d_out;

    char* ws = (char*)d_ws;
    unsigned short* xb = (unsigned short*)ws;                   // 32 MiB bf16 x
    unsigned short* Wb = (unsigned short*)(ws + 33554432);      // 6 MiB bf16 W
    unsigned short* Fb = (unsigned short*)(ws + 39845888);      // 32 MiB bf16 f
    unsigned short* Vb = (unsigned short*)(ws + 73400320);      // 32 MiB bf16 v
    float* Fc  = (float*)(ws);                                  // 2 MiB (aliases xb)
    float* Vc  = (float*)(ws + 2097152);                        // 2 MiB
    float* Hin = (float*)(ws + 4194304);                        // 2 MiB

    cast_all<<<19456, 256, 0, stream>>>(x, Wf, Wi, Wh, xb, Wb);
    gemm_gates<<<2048, 256, 0, stream>>>(xb, Wb, bfp, bip, bhp, Fb, Vb);
    scan1_kernel<<<BB * NC, 256, 0, stream>>>(Fb, Vb, Fc, Vc);
    scan2_kernel<<<16, 256, 0, stream>>>(h0, Fc, Vc, Hin);
    scan3_kernel<<<BB * NC, 256, 0, stream>>>(Fb, Vb, Hin, out);
}